// Round 1
// baseline (749.447 us; speedup 1.0000x reference)
//
#include <hip/hip_runtime.h>

// NARX forward, fp32 VALU baseline.
// x: (4096, 1024, 8) f32; out: (4096, 1024, 1) f32.
// Per point t>=3: feat(32) -> relu(W_in.feat + b_in) -> tanh(W_ih.h + b_ih + b_hh) -> W_out.a + b_out
// t<3: out = x[t,g,7].

#define NGROUP 1024
#define NTIME  4096

__global__ __launch_bounds__(256) void narx_fwd(
    const float* __restrict__ x,
    const float* __restrict__ W_in,
    const float* __restrict__ b_in,
    const float* __restrict__ W_ih,
    const float* __restrict__ b_ih,
    const float* __restrict__ b_hh,
    const float* __restrict__ W_out,
    const float* __restrict__ b_out,
    float* __restrict__ out)
{
    const int idx = blockIdx.x * 256 + threadIdx.x;
    const int t = idx >> 10;          // / NGROUP
    if (t < 3) {                       // first 12 blocks, block-uniform branch
        out[idx] = x[idx * 8 + 7];
        return;
    }
    const int g = idx & (NGROUP - 1);

    // Load x[t-1], x[t-2], x[t-3] rows (8 floats each) as float4 pairs.
    const float4* __restrict__ x4 = reinterpret_cast<const float4*>(x);
    const int b1 = (((t - 1) << 10) + g) << 1;
    const int b2 = (((t - 2) << 10) + g) << 1;
    const int b3 = (((t - 3) << 10) + g) << 1;
    const float4 p1a = x4[b1], p1b = x4[b1 + 1];
    const float4 p2a = x4[b2], p2b = x4[b2 + 1];
    const float4 p3a = x4[b3], p3b = x4[b3 + 1];

    const float xm1[8] = {p1a.x, p1a.y, p1a.z, p1a.w, p1b.x, p1b.y, p1b.z, p1b.w};
    const float xm2[8] = {p2a.x, p2a.y, p2a.z, p2a.w, p2b.x, p2b.y, p2b.z, p2b.w};
    const float xm3[8] = {p3a.x, p3a.y, p3a.z, p3a.w, p3b.x, p3b.y, p3b.z, p3b.w};

    // Feature layout per reference:
    // feat[d*7+f] = x[t+off_x[d], g, f], off_x = {-1,-3,-2,-1}, f=0..6
    // feat[28+d]  = x[t+off_y[d], g, 7], off_y = {-1,-3,-2,-1}
    float feat[32];
#pragma unroll
    for (int f = 0; f < 7; ++f) {
        feat[f]      = xm1[f];
        feat[7 + f]  = xm3[f];
        feat[14 + f] = xm2[f];
        feat[21 + f] = xm1[f];
    }
    feat[28] = xm1[7];
    feat[29] = xm3[7];
    feat[30] = xm2[7];
    feat[31] = xm1[7];

    // Layer 1: h = relu(W_in . feat + b_in). Fully unrolled -> feat/h static-indexed,
    // W_in addresses uniform -> scalar loads, v_fmac with SGPR operand.
    float h[64];
#pragma unroll
    for (int o = 0; o < 64; ++o) {
        float acc = b_in[o];
#pragma unroll
        for (int i = 0; i < 32; ++i)
            acc = fmaf(W_in[o * 32 + i], feat[i], acc);
        h[o] = fmaxf(acc, 0.0f);
    }

    // Layer 2 + 3 fused: y = sum_o2 W_out[o2] * tanh(W_ih[o2,:].h + b_ih[o2] + b_hh[o2]) + b_out
    float y = b_out[0];
#pragma unroll 1
    for (int o2 = 0; o2 < 64; ++o2) {
        float acc = b_ih[o2] + b_hh[o2];
        const float* __restrict__ wrow = W_ih + o2 * 64;
#pragma unroll
        for (int o = 0; o < 64; ++o)
            acc = fmaf(wrow[o], h[o], acc);
        // tanh(z) = 1 - 2/(exp(2z)+1), clamped to avoid inf/inf
        const float z = fminf(fmaxf(acc, -15.0f), 15.0f);
        const float e = __expf(2.0f * z);
        const float a = 1.0f - 2.0f * __builtin_amdgcn_rcpf(e + 1.0f);
        y = fmaf(W_out[o2], a, y);
    }

    out[idx] = y;
}

extern "C" void kernel_launch(void* const* d_in, const int* in_sizes, int n_in,
                              void* d_out, int out_size, void* d_ws, size_t ws_size,
                              hipStream_t stream) {
    const float* x     = (const float*)d_in[0];
    const float* W_in  = (const float*)d_in[1];
    const float* b_in  = (const float*)d_in[2];
    const float* W_ih  = (const float*)d_in[3];
    const float* b_ih  = (const float*)d_in[4];
    // d_in[5] = W_hh: unused in the reference forward
    const float* b_hh  = (const float*)d_in[6];
    const float* W_out = (const float*)d_in[7];
    const float* b_out = (const float*)d_in[8];
    float* out = (float*)d_out;

    const int total  = NTIME * NGROUP;        // 4,194,304
    const int blocks = total / 256;           // 16384, exact
    narx_fwd<<<blocks, 256, 0, stream>>>(x, W_in, b_in, W_ih, b_ih, b_hh, W_out, b_out, out);
}

// Round 2
// 186.429 us; speedup vs baseline: 4.0200x; 4.0200x over previous
//
#include <hip/hip_runtime.h>

// NARX forward via bf16 MFMA (16x16x32), points-as-N formulation.
// D1 = W_in(64x32) . F^T(32x16pts)  -> H^T tiles, relu, bf16 -> LDS
// D2 = W_ih(64x64) . H^T(64x16pts)  -> Pade-tanh -> dot W_out -> out
// Per-wave LDS scratch only (no cross-wave sharing, no barriers).

typedef __attribute__((ext_vector_type(8))) short bf16x8;
typedef __attribute__((ext_vector_type(4))) float f32x4;

__device__ __forceinline__ unsigned short f2bf(float f) {
    unsigned u = __builtin_bit_cast(unsigned, f);
    u += 0x7fffu + ((u >> 16) & 1u);          // round-to-nearest-even
    return (unsigned short)(u >> 16);
}
__device__ __forceinline__ unsigned pk2(float lo, float hi) {
    return (unsigned)f2bf(lo) | ((unsigned)f2bf(hi) << 16);
}

union BF8 { bf16x8 v; unsigned u[4]; };

__global__ __launch_bounds__(256, 2) void narx_mfma(
    const float* __restrict__ x, const float* __restrict__ W_in, const float* __restrict__ b_in,
    const float* __restrict__ W_ih, const float* __restrict__ b_ih, const float* __restrict__ b_hh,
    const float* __restrict__ W_out, const float* __restrict__ b_out, float* __restrict__ out)
{
    // Per-wave scratch: F = feature tile (128 pts x 32 bf16, 16B-chunk XOR-swizzled),
    // H = hidden tile (16 pts x 64 bf16, row padded to 72 for bank spread).
    __shared__ unsigned short F[4][128][32];
    __shared__ unsigned short H[4][16][72];

    // bijective XCD-aware swizzle (m204 form): consecutive t-blocks share an XCD -> L2 reuse of x rows
    const int nwg  = gridDim.x;
    const int orig = blockIdx.x;
    const int q8 = nwg >> 3, r8 = nwg & 7;
    const int xcd = orig & 7, inner = orig >> 3;
    const int b = (xcd < r8 ? xcd * (q8 + 1) : r8 * (q8 + 1) + (xcd - r8) * q8) + inner;

    const int lane = threadIdx.x & 63;
    const int w    = threadIdx.x >> 6;   // wave 0..3
    const int c    = lane >> 4;          // K-chunk / quarter group
    const int pl   = lane & 15;          // point (or row) within 16-tile
    const int pt0  = 3072 + b * 512 + w * 128;   // wave's first flattened point (t*1024+g)

    // ---- preload weight fragments (A-operands) ----
    bf16x8 wa[4];                        // W_in tiles: A[row=pl][k=8c+j] = W_in[16T+pl][8c+j]
    #pragma unroll
    for (int T = 0; T < 4; ++T) {
        const float* p = W_in + (16*T + pl) * 32 + 8*c;
        float4 u0 = *(const float4*)p, u1 = *(const float4*)(p + 4);
        BF8 t; t.u[0]=pk2(u0.x,u0.y); t.u[1]=pk2(u0.z,u0.w); t.u[2]=pk2(u1.x,u1.y); t.u[3]=pk2(u1.z,u1.w);
        wa[T] = t.v;
    }
    bf16x8 wi[2][4];                     // W_ih tiles: A[row=pl][k=32k0+8c+j]
    #pragma unroll
    for (int k0 = 0; k0 < 2; ++k0)
    #pragma unroll
    for (int U = 0; U < 4; ++U) {
        const float* p = W_ih + (16*U + pl) * 64 + 32*k0 + 8*c;
        float4 u0 = *(const float4*)p, u1 = *(const float4*)(p + 4);
        BF8 t; t.u[0]=pk2(u0.x,u0.y); t.u[1]=pk2(u0.z,u0.w); t.u[2]=pk2(u1.x,u1.y); t.u[3]=pk2(u1.z,u1.w);
        wi[k0][U] = t.v;
    }
    // per-lane bias/output-weight slices: index 16T + 4c + q  (matches C/D row = (l>>4)*4+q)
    f32x4 bin[4], bias2[4], wo[4];
    #pragma unroll
    for (int T = 0; T < 4; ++T) {
        bin[T]  = *(const f32x4*)(b_in  + 16*T + 4*c);
        f32x4 bi = *(const f32x4*)(b_ih + 16*T + 4*c);
        f32x4 bh = *(const f32x4*)(b_hh + 16*T + 4*c);
        bias2[T] = bi + bh;
        wo[T]   = *(const f32x4*)(W_out + 16*T + 4*c);
    }
    const float bout = b_out[0];

    #pragma unroll
    for (int half = 0; half < 2; ++half) {
        // ---- build 64 feature rows (1 pt per lane, uniform code) ----
        {
            const int p = pt0 + half*64 + lane;
            const int t = p >> 10, g = p & 1023;
            const float4* xr = (const float4*)x;
            const int base1 = ((t-1)*1024 + g)*2;
            const int base2 = ((t-2)*1024 + g)*2;
            const int base3 = ((t-3)*1024 + g)*2;
            float4 a0 = xr[base1], a1 = xr[base1+1];   // x[t-1,g,0:4 / 4:8]
            float4 b0 = xr[base2], b1 = xr[base2+1];   // x[t-2,...]
            float4 c0 = xr[base3], c1 = xr[base3+1];   // x[t-3,...]
            // feat layout: [xm1 0..6, xm3 0][xm3 1..6, xm2 0..1][xm2 2..6, xm1 0..2][xm1 3..7, xm3 7, xm2 7, xm1 7]
            uint4 q0 = make_uint4(pk2(a0.x,a0.y), pk2(a0.z,a0.w), pk2(a1.x,a1.y), pk2(a1.z,c0.x));
            uint4 q1 = make_uint4(pk2(c0.y,c0.z), pk2(c0.w,c1.x), pk2(c1.y,c1.z), pk2(b0.x,b0.y));
            uint4 q2 = make_uint4(pk2(b0.z,b0.w), pk2(b1.x,b1.y), pk2(b1.z,a0.x), pk2(a0.y,a0.z));
            uint4 q3 = make_uint4(pk2(a0.w,a1.x), pk2(a1.y,a1.z), pk2(a1.w,c1.w), pk2(b1.w,a1.w));
            const int lp = half*64 + lane;
            const int s  = (lp >> 1) & 3;              // 16B-chunk XOR swizzle -> bank floor
            uint4* Frow = (uint4*)&F[w][lp][0];
            Frow[0 ^ s] = q0; Frow[1 ^ s] = q1; Frow[2 ^ s] = q2; Frow[3 ^ s] = q3;
        }
        asm volatile("s_waitcnt lgkmcnt(0)" ::: "memory");   // cross-lane LDS dep within wave

        #pragma unroll
        for (int rb = 0; rb < 4; ++rb) {
            const int base = half*64 + rb*16;
            const int lp   = base + pl;
            // B1-frag: B[k=8c+j][pt=pl] = feat_pt[8c+j]
            bf16x8 bf1 = *(bf16x8*)&F[w][lp][(c ^ ((lp >> 1) & 3)) * 8];

            f32x4 d1[4];
            #pragma unroll
            for (int T = 0; T < 4; ++T)
                d1[T] = __builtin_amdgcn_mfma_f32_16x16x32_bf16(wa[T], bf1, bin[T], 0, 0, 0);

            // relu -> bf16 -> H[pt][h] (lane holds h = 16T+4c+q, pt = pl; 4 consecutive h = 8B write)
            #pragma unroll
            for (int T = 0; T < 4; ++T) {
                float h0 = fmaxf(d1[T][0], 0.f), h1 = fmaxf(d1[T][1], 0.f);
                float h2 = fmaxf(d1[T][2], 0.f), h3 = fmaxf(d1[T][3], 0.f);
                *(uint2*)&H[w][pl][16*T + 4*c] = make_uint2(pk2(h0,h1), pk2(h2,h3));
            }
            asm volatile("s_waitcnt lgkmcnt(0)" ::: "memory");

            // B2-frags: B[k][pt] = H[pl][k], k = 8c+j (+32)
            bf16x8 bh0 = *(bf16x8*)&H[w][pl][8*c];
            bf16x8 bh1 = *(bf16x8*)&H[w][pl][32 + 8*c];

            f32x4 d2[4];
            #pragma unroll
            for (int U = 0; U < 4; ++U) {
                d2[U] = __builtin_amdgcn_mfma_f32_16x16x32_bf16(wi[0][U], bh0, bias2[U], 0, 0, 0);
                d2[U] = __builtin_amdgcn_mfma_f32_16x16x32_bf16(wi[1][U], bh1, d2[U],   0, 0, 0);
            }

            // Pade(5,4) tanh (clamped +-4, max err ~2.3e-3) + W_out dot
            float part = 0.f;
            #pragma unroll
            for (int U = 0; U < 4; ++U) {
                #pragma unroll
                for (int j = 0; j < 4; ++j) {
                    float z  = fminf(fmaxf(d2[U][j], -4.f), 4.f);
                    float p2 = z * z;
                    float num = z * fmaf(p2, p2 + 105.f, 945.f);
                    float den = fmaf(p2, fmaf(p2, 15.f, 420.f), 945.f);
                    part = fmaf(wo[U][j], num * __builtin_amdgcn_rcpf(den), part);
                }
            }
            // reduce partials across the 4 lane-groups (same pt at lanes pl, pl+16, pl+32, pl+48)
            part += __shfl_xor(part, 16);
            part += __shfl_xor(part, 32);
            if (lane < 16)
                out[pt0 + base + lane] = part + bout;
        }
    }
}

__global__ __launch_bounds__(256) void narx_pass(const float* __restrict__ x, float* __restrict__ out) {
    const int i = blockIdx.x * 256 + threadIdx.x;   // i < 3072
    out[i] = x[i * 8 + 7];
}

extern "C" void kernel_launch(void* const* d_in, const int* in_sizes, int n_in,
                              void* d_out, int out_size, void* d_ws, size_t ws_size,
                              hipStream_t stream) {
    const float* x     = (const float*)d_in[0];
    const float* W_in  = (const float*)d_in[1];
    const float* b_in  = (const float*)d_in[2];
    const float* W_ih  = (const float*)d_in[3];
    const float* b_ih  = (const float*)d_in[4];
    // d_in[5] = W_hh: unused in the reference forward
    const float* b_hh  = (const float*)d_in[6];
    const float* W_out = (const float*)d_in[7];
    const float* b_out = (const float*)d_in[8];
    float* out = (float*)d_out;

    // points m in [3072, 4096*1024): 4,191,232 = 8186 blocks * 512 pts
    narx_mfma<<<8186, 256, 0, stream>>>(x, W_in, b_in, W_ih, b_ih, b_hh, W_out, b_out, out);
    narx_pass<<<12, 256, 0, stream>>>(x, out);      // t < 3 passthrough
}